// Round 8
// baseline (114.924 us; speedup 1.0000x reference)
//
#include <hip/hip_runtime.h>

// Problem constants
#define B_   32
#define T_   2048
#define IN_  1024
#define OUT_ 256
#define M_   (B_ * T_)   // 65536

// MFMA GEMM tiling: full-N block tile so A is read exactly once.
// BK=32, triple-buffered staging (counted-vmcnt pipeline), 2 blocks/CU.
#define BM 128
#define BN 256
#define BK 32
#define NSTEPS (IN_ / BK)   // 32
#define THREADS 512

// Scan chunking: LC=32 so one BM=128 GEMM block covers exactly 4 chunks.
#define LC 32
#define NC (T_ / LC)        // 64 chunks per batch
#define XPAD 264            // LDS x-tile row pitch (bf16), 528B rows (16B-aligned)

// LDS: staging = 3*8KB (A) + 3*16KB (B) = 72 KB ; x-tile = 128*264*2 = 66 KB
#define ABUF_OFF(c) ((c) * (BM * BK * 2))                      // 8 KB each, 3x
#define BBUF_OFF(c) (3 * (BM * BK * 2) + (c) * (BN * BK * 2))  // 16 KB each, 3x
#define SMEM_BYTES (3 * (BM * BK * 2) + 3 * (BN * BK * 2))     // 73728

typedef __attribute__((ext_vector_type(4))) float f32x4;
typedef __attribute__((ext_vector_type(8))) __bf16 bf16x8;

// fp32 -> bf16 round-to-nearest-even
__device__ __forceinline__ unsigned int f2bf_pk(float a, float b) {
    unsigned int ua = __float_as_uint(a);
    unsigned int ub = __float_as_uint(b);
    ua = (ua + 0x7fffu + ((ua >> 16) & 1u)) >> 16;
    ub = (ub + 0x7fffu + ((ub >> 16) & 1u)) >> 16;
    return ua | (ub << 16);
}
__device__ __forceinline__ unsigned short f2bf1(float a) {
    unsigned int ua = __float_as_uint(a);
    return (unsigned short)((ua + 0x7fffu + ((ua >> 16) & 1u)) >> 16);
}
__device__ __forceinline__ float bf2f(unsigned short s) {
    return __uint_as_float((unsigned int)s << 16);
}

// async global -> LDS, 16B per lane; lds dest = wave-uniform base + lane*16
__device__ __forceinline__ void gload_lds16(const void* g, void* l) {
    __builtin_amdgcn_global_load_lds(
        (const __attribute__((address_space(1))) void*)g,
        (__attribute__((address_space(3))) void*)l, 16, 0, 0);
}

// ---------------------------------------------------------------------------
// One-shot W fp32 -> bf16 into workspace (512 KB).
// ---------------------------------------------------------------------------
__global__ __launch_bounds__(256) void convert_w(const float* __restrict__ W,
                                                 unsigned short* __restrict__ Wb) {
    const int i = blockIdx.x * 256 + threadIdx.x;  // float4 index
    const float4 v = ((const float4*)W)[i];
    uint2 o;
    o.x = f2bf_pk(v.x, v.y);
    o.y = f2bf_pk(v.z, v.w);
    ((uint2*)Wb)[i] = o;
}

// ---------------------------------------------------------------------------
// Fused bf16 MFMA GEMM + chunk-local scan.
// Counted-vmcnt pipeline (T3/T4): 3-deep A/B staging buffers, raw s_barrier
// with lgkmcnt(0) only, explicit vmcnt(2) at iter start -> B(i+1)'s HBM
// latency spans a full iteration, never drained to 0 in the main loop.
// Queue invariant entering iter i: [B(i)x2, A(i+1)x2, B(i+1)x2].
// Slot reuse is separated by >=1 barrier (3-deep rotation).
// ---------------------------------------------------------------------------
__global__ __launch_bounds__(THREADS, 4) void gemm_fused(
    const float* __restrict__ A, const unsigned short* __restrict__ Wb,
    const float* __restrict__ bias, const float* __restrict__ decay,
    unsigned short* __restrict__ Xb, float* __restrict__ chunkend) {
    __shared__ __align__(16) char smem[SMEM_BYTES];

    const int tid  = threadIdx.x;
    const int lane = tid & 63;
    const int wid  = tid >> 6;
    const int wm   = wid >> 2;     // 0..1  (M direction)
    const int wn   = wid & 3;      // 0..3  (N direction)
    const int l15  = lane & 15;
    const int l4   = lane >> 4;    // 0..3
    const int bm0  = blockIdx.x * BM;

    // --- A staging: 1 granule (8 elems) per thread. q=tid -> row=q>>2, g=q&3.
    const int rowA = tid >> 2;
    const int gA   = tid & 3;
    const float* gsrcA = A + (size_t)(bm0 + rowA) * IN_ + gA * 8;
    const int ldsA = rowA * BK + ((gA ^ (rowA & 3)) << 3);   // elements

    // --- B staging via global_load_lds: 2 instrs/wave, linear LDS dest.
    // Source granule = g_lin ^ (row&3) (involution; read uses same XOR).
    const unsigned short* gsrcB[2];
    int ldsBbase[2];   // byte offset of wave-uniform LDS dest (within Bbuf)
#pragma unroll
    for (int i = 0; i < 2; ++i) {
        const int q = (wid + i * 8) * 64 + lane;
        const int r = q >> 2;
        const int g = (q & 3) ^ (r & 3);
        gsrcB[i] = Wb + (size_t)r * IN_ + g * 8;
        ldsBbase[i] = (wid + i * 8) * 1024;   // bytes; +lane*16 added by HW
    }

    f32x4 acc[4][4] = {};
    float4 a0, a1;

    // --- prologue ---
    // issue B(0) -> bbuf[0]
    gload_lds16(gsrcB[0], smem + BBUF_OFF(0) + ldsBbase[0]);
    gload_lds16(gsrcB[1], smem + BBUF_OFF(0) + ldsBbase[1]);
    // A(0) -> regs, pack -> abuf[0] (compiler inserts the vmcnt; one-time drain ok)
    a0 = *(const float4*)(gsrcA);
    a1 = *(const float4*)(gsrcA + 4);
    {
        int4 w;
        w.x = f2bf_pk(a0.x, a0.y); w.y = f2bf_pk(a0.z, a0.w);
        w.z = f2bf_pk(a1.x, a1.y); w.w = f2bf_pk(a1.z, a1.w);
        *(int4*)(smem + ABUF_OFF(0) + ldsA * 2) = w;
    }
    // issue A(1) -> regs
    a0 = *(const float4*)(gsrcA + BK);
    a1 = *(const float4*)(gsrcA + BK + 4);
    asm volatile("s_waitcnt lgkmcnt(0)" ::: "memory");
    __builtin_amdgcn_s_barrier();
    __builtin_amdgcn_sched_barrier(0);
    // issue B(1) -> bbuf[1]
    gload_lds16(gsrcB[0] + BK, smem + BBUF_OFF(1) + ldsBbase[0]);
    gload_lds16(gsrcB[1] + BK, smem + BBUF_OFF(1) + ldsBbase[1]);
    // queue now: [A(1)x2, B(1)x2]

    for (int i = 0; i < NSTEPS; ++i) {
        // (a) counted wait: retire B(i) (+A(i+1)); keep B(i+1) in flight
        if (i + 1 < NSTEPS) {
            asm volatile("s_waitcnt vmcnt(2)" ::: "memory");
        } else {
            asm volatile("s_waitcnt vmcnt(0)" ::: "memory");
        }
        __builtin_amdgcn_sched_barrier(0);
        // (b) pack A(i+1) -> abuf[(i+1)%3]
        if (i + 1 < NSTEPS) {
            int4 w;
            w.x = f2bf_pk(a0.x, a0.y); w.y = f2bf_pk(a0.z, a0.w);
            w.z = f2bf_pk(a1.x, a1.y); w.w = f2bf_pk(a1.z, a1.w);
            *(int4*)(smem + ABUF_OFF((i + 1) % 3) + ldsA * 2) = w;
        }
        // (c) issue A(i+2) -> regs
        if (i + 2 < NSTEPS) {
            const int k0 = (i + 2) * BK;
            a0 = *(const float4*)(gsrcA + k0);
            a1 = *(const float4*)(gsrcA + k0 + 4);
        }
        // (d) barrier WITHOUT vmcnt drain
        asm volatile("s_waitcnt lgkmcnt(0)" ::: "memory");
        __builtin_amdgcn_s_barrier();
        __builtin_amdgcn_sched_barrier(0);
        // (e) issue B(i+2) -> bbuf[(i+2)%3] (slot last read at iter i-1, pre-barrier)
        if (i + 2 < NSTEPS) {
            const int k0 = (i + 2) * BK;
            gload_lds16(gsrcB[0] + k0, smem + BBUF_OFF((i + 2) % 3) + ldsBbase[0]);
            gload_lds16(gsrcB[1] + k0, smem + BBUF_OFF((i + 2) % 3) + ldsBbase[1]);
        }
        // (f) compute on abuf[i%3], bbuf[i%3]
        {
            const unsigned short* Ab = (const unsigned short*)(smem + ABUF_OFF(i % 3));
            const unsigned short* Bb = (const unsigned short*)(smem + BBUF_OFF(i % 3));
            bf16x8 af[4], bfv[4];
#pragma unroll
            for (int mi = 0; mi < 4; ++mi) {
                const int row = wm * 64 + mi * 16 + l15;
                af[mi] = *(const bf16x8*)&Ab[row * BK + ((l4 ^ (row & 3)) << 3)];
            }
#pragma unroll
            for (int ni = 0; ni < 4; ++ni) {
                const int col = wn * 64 + ni * 16 + l15;
                bfv[ni] = *(const bf16x8*)&Bb[col * BK + ((l4 ^ (col & 3)) << 3)];
            }
#pragma unroll
            for (int mi = 0; mi < 4; ++mi)
#pragma unroll
                for (int ni = 0; ni < 4; ++ni)
                    acc[mi][ni] = __builtin_amdgcn_mfma_f32_16x16x32_bf16(
                        af[mi], bfv[ni], acc[mi][ni], 0, 0, 0);
        }
    }
    __syncthreads();   // staging region becomes the x-tile now

    // --- epilogue part 1: x = acc + bias -> bf16 into LDS tile [128][XPAD] ---
    unsigned short* xt = (unsigned short*)smem;
#pragma unroll
    for (int ni = 0; ni < 4; ++ni) {
        const int col = wn * 64 + ni * 16 + l15;
        const float bv = bias[col];
#pragma unroll
        for (int mi = 0; mi < 4; ++mi) {
            const int r0 = wm * 64 + mi * 16 + (l4 << 2);
#pragma unroll
            for (int r = 0; r < 4; ++r)
                xt[(r0 + r) * XPAD + col] = f2bf1(acc[mi][ni][r] + bv);
        }
    }
    __syncthreads();

    const int b  = bm0 >> 11;          // batch index (T = 2048)
    const int c0 = (bm0 >> 5) & 63;    // first chunk id within batch (LC = 32)

    // --- epilogue part 2: dump x tile to global ws (coalesced short8) ---
    {
        const int cr = tid >> 5;             // 0..15
        const int cg = (tid & 31) << 3;      // 8-col granule
#pragma unroll
        for (int it = 0; it < 8; ++it) {
            const int row = it * 16 + cr;
            bf16x8 v = *(const bf16x8*)&xt[row * XPAD + cg];
            *(bf16x8*)&Xb[(size_t)(bm0 + row) * OUT_ + cg] = v;
        }
    }

    // --- epilogue part 3: chunk-local scans (seed 0) -> chunkend ---
    for (int task = tid; task < 4 * OUT_; task += THREADS) {
        const int cl  = task >> 8;       // 0..3 chunk within block
        const int col = task & 255;
        const float alpha = decay[col];
        const float om = 1.0f - alpha;
        float u = 0.0f;
        const unsigned short* p = &xt[(cl * LC) * XPAD + col];
#pragma unroll
        for (int t = 0; t < LC; ++t)
            u = fmaf(alpha, u, om * bf2f(p[t * XPAD]));
        chunkend[(size_t)(b * NC + c0 + cl) * OUT_ + col] = u;
    }
}

// ---------------------------------------------------------------------------
// Carry pass: fold NC=64 chunkends per batch; batched loads then in-register
// dependent chain (same fp order as sequential).
// ---------------------------------------------------------------------------
__global__ __launch_bounds__(OUT_) void carry_pass(const float* __restrict__ chunkend,
                                                   const float* __restrict__ decay,
                                                   float* __restrict__ carryin) {
    const int b = blockIdx.x;
    const int o = threadIdx.x;
    const float alpha = decay[o];
    float aL = alpha;
#pragma unroll
    for (int i = 1; i < LC; ++i) aL *= alpha;   // alpha^LC

    float ce[NC];
#pragma unroll
    for (int c = 0; c < NC; ++c)
        ce[c] = chunkend[(size_t)(b * NC + c) * OUT_ + o];

    float carry = 0.0f;
#pragma unroll
    for (int c = 0; c < NC; ++c) {
        carryin[(size_t)(b * NC + c) * OUT_ + o] = carry;
        carry = fmaf(aL, carry, ce[c]);
    }
}

// ---------------------------------------------------------------------------
// Final scan: 2048 independent (b,chunk) wave-units, 4 cols/thread.
// ---------------------------------------------------------------------------
__global__ __launch_bounds__(256) void scan_final(const unsigned short* __restrict__ Xb,
                                                  const float* __restrict__ decay,
                                                  const float* __restrict__ carryin,
                                                  float* __restrict__ out) {
    const int unit = blockIdx.x * 4 + (threadIdx.x >> 6);  // == b*NC + c
    const int l    = threadIdx.x & 63;
    const int col  = l << 2;
    const int b    = unit >> 6;
    const int c    = unit & 63;

    const float4 al = *(const float4*)&decay[col];
    const float4 om = {1.0f - al.x, 1.0f - al.y, 1.0f - al.z, 1.0f - al.w};
    float4 u = *(const float4*)&carryin[(size_t)unit * OUT_ + col];

    const size_t base = (size_t)(b * T_ + c * LC) * OUT_ + col;
#pragma unroll 8
    for (int t = 0; t < LC; ++t) {
        const ushort4 xv = *(const ushort4*)&Xb[base + (size_t)t * OUT_];
        u.x = fmaf(al.x, u.x, om.x * bf2f(xv.x));
        u.y = fmaf(al.y, u.y, om.y * bf2f(xv.y));
        u.z = fmaf(al.z, u.z, om.z * bf2f(xv.z));
        u.w = fmaf(al.w, u.w, om.w * bf2f(xv.w));
        *(float4*)&out[base + (size_t)t * OUT_] = u;
    }
}

// ---------------------------------------------------------------------------
// Fallback path (ws too small): fp32 GEMM + simple scan, known good.
// ---------------------------------------------------------------------------
__global__ __launch_bounds__(256) void gemm_bias(const float* __restrict__ A,
                                                 const float* __restrict__ W,
                                                 const float* __restrict__ bias,
                                                 float* __restrict__ C) {
    __shared__ float As[16][64 + 4];
    __shared__ float Ws[16][64 + 4];
    const int bm = blockIdx.y * 64;
    const int bn = blockIdx.x * 64;
    const int tid = threadIdx.x;
    const int tx = tid & 15, ty = tid >> 4;
    const int lr = tid >> 2, lc = (tid & 3) << 2;
    float acc[4][4] = {};
    const float* Ap = A + (size_t)(bm + lr) * IN_ + lc;
    const float* Wp = W + (size_t)(bn + lr) * IN_ + lc;
    for (int k0 = 0; k0 < IN_; k0 += 16) {
        const float4 a = *(const float4*)(Ap + k0);
        const float4 w = *(const float4*)(Wp + k0);
        __syncthreads();
        As[lc + 0][lr] = a.x; As[lc + 1][lr] = a.y; As[lc + 2][lr] = a.z; As[lc + 3][lr] = a.w;
        Ws[lc + 0][lr] = w.x; Ws[lc + 1][lr] = w.y; Ws[lc + 2][lr] = w.z; Ws[lc + 3][lr] = w.w;
        __syncthreads();
#pragma unroll
        for (int kk = 0; kk < 16; ++kk) {
            const float4 av = *(const float4*)&As[kk][ty << 2];
            const float4 wv = *(const float4*)&Ws[kk][tx << 2];
            const float a0[4] = {av.x, av.y, av.z, av.w};
            const float w0[4] = {wv.x, wv.y, wv.z, wv.w};
#pragma unroll
            for (int i = 0; i < 4; ++i)
#pragma unroll
                for (int j = 0; j < 4; ++j) acc[i][j] = fmaf(a0[i], w0[j], acc[i][j]);
        }
    }
#pragma unroll
    for (int i = 0; i < 4; ++i) {
        const size_t row = (size_t)(bm + (ty << 2) + i);
#pragma unroll
        for (int j = 0; j < 4; ++j)
            C[row * OUT_ + bn + (tx << 2) + j] = acc[i][j] + bias[bn + (tx << 2) + j];
    }
}

__global__ __launch_bounds__(OUT_) void scan_simple(float* __restrict__ C,
                                                    const float* __restrict__ decay) {
    const int b = blockIdx.x;
    const int o = threadIdx.x;
    const float alpha = decay[o];
    const float om = 1.0f - alpha;
    float u = 0.0f;
    float* p = C + (size_t)b * T_ * OUT_ + o;
    for (int t = 0; t < T_; ++t) {
        const float x = p[(size_t)t * OUT_];
        u = fmaf(alpha, u, om * x);
        p[(size_t)t * OUT_] = u;
    }
}

extern "C" void kernel_launch(void* const* d_in, const int* in_sizes, int n_in,
                              void* d_out, int out_size, void* d_ws, size_t ws_size,
                              hipStream_t stream) {
    const float* inputs = (const float*)d_in[0];
    const float* weight = (const float*)d_in[1];
    const float* bias   = (const float*)d_in[2];
    const float* decay  = (const float*)d_in[3];
    float* out = (float*)d_out;

    // Workspace layout
    const size_t wb_bytes = (size_t)OUT_ * IN_ * 2;             // 512 KB bf16 W
    const size_t ce_bytes = (size_t)B_ * NC * OUT_ * 4;         // 2 MB chunkend
    const size_t ci_bytes = ce_bytes;                           // 2 MB carryin
    const size_t x_bytes  = (size_t)M_ * OUT_ * 2;              // 32 MB bf16 x
    const size_t need = wb_bytes + ce_bytes + ci_bytes + x_bytes;

    if (ws_size >= need) {
        char* w = (char*)d_ws;
        unsigned short* Wb = (unsigned short*)w;
        float* chunkend    = (float*)(w + wb_bytes);
        float* carryin     = (float*)(w + wb_bytes + ce_bytes);
        unsigned short* Xb = (unsigned short*)(w + wb_bytes + ce_bytes + ci_bytes);

        convert_w<<<(OUT_ * IN_ / 4) / 256, 256, 0, stream>>>(weight, Wb);
        gemm_fused<<<M_ / BM, THREADS, 0, stream>>>(inputs, Wb, bias, decay, Xb, chunkend);
        carry_pass<<<B_, OUT_, 0, stream>>>(chunkend, decay, carryin);
        scan_final<<<(B_ * NC) / 4, 256, 0, stream>>>(Xb, decay, carryin, out);
    } else {
        dim3 g(OUT_ / 64, M_ / 64);
        gemm_bias<<<g, 256, 0, stream>>>(inputs, weight, bias, out);
        scan_simple<<<B_, OUT_, 0, stream>>>(out, decay);
    }
}

// Round 9
// 113.019 us; speedup vs baseline: 1.0169x; 1.0169x over previous
//
#include <hip/hip_runtime.h>

// Problem constants
#define B_   32
#define T_   2048
#define IN_  1024
#define OUT_ 256
#define M_   (B_ * T_)   // 65536

// MFMA GEMM tiling (frozen round-8 core): BK=32, 3-deep counted-vmcnt staging.
#define BM 128
#define BN 256
#define BK 32
#define NSTEPS (IN_ / BK)   // 32
#define THREADS 512
#define TPB 16              // time-tiles (blocks) per batch: T/BM

// Scan chunking: LC=32 so one BM=128 block covers exactly 4 chunks.
#define LC 32
#define XPAD 264            // LDS x-tile row pitch (bf16), 528B rows (16B-aligned)

// LDS: staging = 3*8KB (A) + 3*16KB (B) = 72 KB (dead after main loop)
//      overlay: x-tile 66 KB + ce 4 KB + carry 4 KB = 74 KB
#define ABUF_OFF(c) ((c) * (BM * BK * 2))                      // 8 KB each, 3x
#define BBUF_OFF(c) (3 * (BM * BK * 2) + (c) * (BN * BK * 2))  // 16 KB each, 3x
#define XT_BYTES (BM * XPAD * 2)                               // 67584
#define SMEM_BYTES (XT_BYTES + 8192)                           // 75776 (2 blocks/CU)

typedef __attribute__((ext_vector_type(4))) float f32x4;
typedef __attribute__((ext_vector_type(8))) __bf16 bf16x8;

// fp32 -> bf16 round-to-nearest-even
__device__ __forceinline__ unsigned int f2bf_pk(float a, float b) {
    unsigned int ua = __float_as_uint(a);
    unsigned int ub = __float_as_uint(b);
    ua = (ua + 0x7fffu + ((ua >> 16) & 1u)) >> 16;
    ub = (ub + 0x7fffu + ((ub >> 16) & 1u)) >> 16;
    return ua | (ub << 16);
}
__device__ __forceinline__ unsigned short f2bf1(float a) {
    unsigned int ua = __float_as_uint(a);
    return (unsigned short)((ua + 0x7fffu + ((ua >> 16) & 1u)) >> 16);
}
__device__ __forceinline__ float bf2f(unsigned short s) {
    return __uint_as_float((unsigned int)s << 16);
}

// async global -> LDS, 16B per lane; lds dest = wave-uniform base + lane*16
__device__ __forceinline__ void gload_lds16(const void* g, void* l) {
    __builtin_amdgcn_global_load_lds(
        (const __attribute__((address_space(1))) void*)g,
        (__attribute__((address_space(3))) void*)l, 16, 0, 0);
}

// ---------------------------------------------------------------------------
// One-shot W fp32 -> bf16 (512 KB) + zero the ticket/flag region (block 0).
// Kernel-boundary release makes both visible to the fused kernel.
// ---------------------------------------------------------------------------
__global__ __launch_bounds__(256) void convert_w_init(const float* __restrict__ W,
                                                      unsigned short* __restrict__ Wb,
                                                      unsigned int* __restrict__ flags) {
    const int i = blockIdx.x * 256 + threadIdx.x;  // float4 index
    const float4 v = ((const float4*)W)[i];
    uint2 o;
    o.x = f2bf_pk(v.x, v.y);
    o.y = f2bf_pk(v.z, v.w);
    ((uint2*)Wb)[i] = o;
    if (blockIdx.x == 0) {
        flags[threadIdx.x] = 0u;
        flags[256 + threadIdx.x] = 0u;
        if (threadIdx.x == 0) flags[512] = 0u;   // ticket
    }
}

// ---------------------------------------------------------------------------
// Single fused kernel: bf16 MFMA GEMM (x stays in LDS) + chunk-local scans
// + decoupled-lookback carry exchange (raking fold, no serial chain) +
// final scan written straight to out. Ticket reassignment => waits only go
// backward in start order => deadlock-free at any residency. Cross-XCD
// payloads/flags via __hip_atomic_* AGENT scope (G16).
// ---------------------------------------------------------------------------
__global__ __launch_bounds__(THREADS, 4) void fused_all(
    const float* __restrict__ A, const unsigned short* __restrict__ Wb,
    const float* __restrict__ bias, const float* __restrict__ decay,
    float* __restrict__ out, float* __restrict__ localend,
    unsigned int* __restrict__ flags) {
    __shared__ __align__(16) char smem[SMEM_BYTES];
    __shared__ int s_tk;

    const int tid  = threadIdx.x;
    const int lane = tid & 63;
    const int wid  = tid >> 6;
    const int wm   = wid >> 2;     // 0..1  (M direction)
    const int wn   = wid & 3;      // 0..3  (N direction)
    const int l15  = lane & 15;
    const int l4   = lane >> 4;    // 0..3

    if (tid == 0) s_tk = (int)atomicAdd(&flags[512], 1u);   // device-scope ticket
    __syncthreads();
    const int p    = s_tk;           // m-tile position, 0..511
    const int jb   = p & (TPB - 1);  // tile index within batch
    const int base = p - jb;         // first tile of this batch
    const int bm0  = p * BM;

    // --- A staging: 1 granule (8 elems) per thread. q=tid -> row=q>>2, g=q&3.
    const int rowA = tid >> 2;
    const int gA   = tid & 3;
    const float* gsrcA = A + (size_t)(bm0 + rowA) * IN_ + gA * 8;
    const int ldsA = rowA * BK + ((gA ^ (rowA & 3)) << 3);   // elements

    // --- B staging via global_load_lds (pre-swizzled source involution).
    const unsigned short* gsrcB[2];
    int ldsBbase[2];
#pragma unroll
    for (int i = 0; i < 2; ++i) {
        const int q = (wid + i * 8) * 64 + lane;
        const int r = q >> 2;
        const int g = (q & 3) ^ (r & 3);
        gsrcB[i] = Wb + (size_t)r * IN_ + g * 8;
        ldsBbase[i] = (wid + i * 8) * 1024;
    }

    f32x4 acc[4][4] = {};
    float4 a0, a1;

    // --- prologue (round-8 verified) ---
    gload_lds16(gsrcB[0], smem + BBUF_OFF(0) + ldsBbase[0]);
    gload_lds16(gsrcB[1], smem + BBUF_OFF(0) + ldsBbase[1]);
    a0 = *(const float4*)(gsrcA);
    a1 = *(const float4*)(gsrcA + 4);
    {
        int4 w;
        w.x = f2bf_pk(a0.x, a0.y); w.y = f2bf_pk(a0.z, a0.w);
        w.z = f2bf_pk(a1.x, a1.y); w.w = f2bf_pk(a1.z, a1.w);
        *(int4*)(smem + ABUF_OFF(0) + ldsA * 2) = w;
    }
    a0 = *(const float4*)(gsrcA + BK);
    a1 = *(const float4*)(gsrcA + BK + 4);
    asm volatile("s_waitcnt lgkmcnt(0)" ::: "memory");
    __builtin_amdgcn_s_barrier();
    __builtin_amdgcn_sched_barrier(0);
    gload_lds16(gsrcB[0] + BK, smem + BBUF_OFF(1) + ldsBbase[0]);
    gload_lds16(gsrcB[1] + BK, smem + BBUF_OFF(1) + ldsBbase[1]);

    for (int i = 0; i < NSTEPS; ++i) {
        if (i + 1 < NSTEPS) {
            asm volatile("s_waitcnt vmcnt(2)" ::: "memory");
        } else {
            asm volatile("s_waitcnt vmcnt(0)" ::: "memory");
        }
        __builtin_amdgcn_sched_barrier(0);
        if (i + 1 < NSTEPS) {
            int4 w;
            w.x = f2bf_pk(a0.x, a0.y); w.y = f2bf_pk(a0.z, a0.w);
            w.z = f2bf_pk(a1.x, a1.y); w.w = f2bf_pk(a1.z, a1.w);
            *(int4*)(smem + ABUF_OFF((i + 1) % 3) + ldsA * 2) = w;
        }
        if (i + 2 < NSTEPS) {
            const int k0 = (i + 2) * BK;
            a0 = *(const float4*)(gsrcA + k0);
            a1 = *(const float4*)(gsrcA + k0 + 4);
        }
        asm volatile("s_waitcnt lgkmcnt(0)" ::: "memory");
        __builtin_amdgcn_s_barrier();
        __builtin_amdgcn_sched_barrier(0);
        if (i + 2 < NSTEPS) {
            const int k0 = (i + 2) * BK;
            gload_lds16(gsrcB[0] + k0, smem + BBUF_OFF((i + 2) % 3) + ldsBbase[0]);
            gload_lds16(gsrcB[1] + k0, smem + BBUF_OFF((i + 2) % 3) + ldsBbase[1]);
        }
        {
            const unsigned short* Ab = (const unsigned short*)(smem + ABUF_OFF(i % 3));
            const unsigned short* Bb = (const unsigned short*)(smem + BBUF_OFF(i % 3));
            bf16x8 af[4], bfv[4];
#pragma unroll
            for (int mi = 0; mi < 4; ++mi) {
                const int row = wm * 64 + mi * 16 + l15;
                af[mi] = *(const bf16x8*)&Ab[row * BK + ((l4 ^ (row & 3)) << 3)];
            }
#pragma unroll
            for (int ni = 0; ni < 4; ++ni) {
                const int col = wn * 64 + ni * 16 + l15;
                bfv[ni] = *(const bf16x8*)&Bb[col * BK + ((l4 ^ (col & 3)) << 3)];
            }
#pragma unroll
            for (int mi = 0; mi < 4; ++mi)
#pragma unroll
                for (int ni = 0; ni < 4; ++ni)
                    acc[mi][ni] = __builtin_amdgcn_mfma_f32_16x16x32_bf16(
                        af[mi], bfv[ni], acc[mi][ni], 0, 0, 0);
        }
    }
    __syncthreads();   // staging dead; smem becomes x-tile + ce + carry

    unsigned short* xt = (unsigned short*)smem;
    float* ceL = (float*)(smem + XT_BYTES);        // [4][256] chunk-local ends
    float* caL = ceL + 4 * OUT_;                   // [4][256] chunk carry-ins

    // --- x = acc + bias -> bf16 x-tile [128][XPAD] ---
#pragma unroll
    for (int ni = 0; ni < 4; ++ni) {
        const int col = wn * 64 + ni * 16 + l15;
        const float bv = bias[col];
#pragma unroll
        for (int mi = 0; mi < 4; ++mi) {
            const int r0 = wm * 64 + mi * 16 + (l4 << 2);
#pragma unroll
            for (int r = 0; r < 4; ++r)
                xt[(r0 + r) * XPAD + col] = f2bf1(acc[mi][ni][r] + bv);
        }
    }
    __syncthreads();

    // --- chunk-local scans (seed 0) -> ceL ---
    for (int task = tid; task < 4 * OUT_; task += THREADS) {
        const int cl  = task >> 8;
        const int col = task & 255;
        const float alpha = decay[col];
        const float om = 1.0f - alpha;
        float u = 0.0f;
        const unsigned short* px = &xt[(cl * LC) * XPAD + col];
#pragma unroll
        for (int t = 0; t < LC; ++t)
            u = fmaf(alpha, u, om * bf2f(px[t * XPAD]));
        ceL[cl * OUT_ + col] = u;
    }
    __syncthreads();

    // --- fold 4 chunks -> 128-step block composite; publish (AGENT scope) ---
    float alpha_c = 0.f, a32 = 0.f, a128 = 0.f;
    if (tid < OUT_) {
        alpha_c = decay[tid];
        a32 = alpha_c;
#pragma unroll
        for (int i = 1; i < LC; ++i) a32 *= alpha_c;   // alpha^32
        const float t2 = a32 * a32;
        a128 = t2 * t2;                                // alpha^128
        float le = ceL[tid];
        le = fmaf(a32, le, ceL[OUT_ + tid]);
        le = fmaf(a32, le, ceL[2 * OUT_ + tid]);
        le = fmaf(a32, le, ceL[3 * OUT_ + tid]);
        __hip_atomic_store(&localend[(size_t)p * OUT_ + tid], le,
                           __ATOMIC_RELAXED, __HIP_MEMORY_SCOPE_AGENT);
    }
    __syncthreads();   // all payload stores complete (vmcnt drained) before flag
    if (tid == 0)
        __hip_atomic_store(&flags[p], 1u, __ATOMIC_RELEASE, __HIP_MEMORY_SCOPE_AGENT);
    // --- wait for all predecessor tiles of this batch (raking, no chain) ---
    if (tid < jb) {
        while (__hip_atomic_load(&flags[base + tid], __ATOMIC_ACQUIRE,
                                 __HIP_MEMORY_SCOPE_AGENT) == 0u)
            __builtin_amdgcn_s_sleep(2);
    }
    __syncthreads();

    // --- compose carry-in: fold predecessors' composites with alpha^128 ---
    if (tid < OUT_) {
        float cin = 0.0f;
#pragma unroll
        for (int i = 0; i < TPB - 1; ++i) {
            float v = __hip_atomic_load(&localend[(size_t)(base + i) * OUT_ + tid],
                                        __ATOMIC_RELAXED, __HIP_MEMORY_SCOPE_AGENT);
            if (i < jb) cin = fmaf(a128, cin, v);
        }
        caL[tid] = cin;
        const float c1 = fmaf(a32, cin, ceL[tid]);
        const float c2 = fmaf(a32, c1, ceL[OUT_ + tid]);
        const float c3 = fmaf(a32, c2, ceL[2 * OUT_ + tid]);
        caL[OUT_ + tid] = c1;
        caL[2 * OUT_ + tid] = c2;
        caL[3 * OUT_ + tid] = c3;
    }
    __syncthreads();

    // --- final scan: seed from chunk carry, write u straight to out ---
    for (int task = tid; task < 4 * OUT_; task += THREADS) {
        const int cl  = task >> 8;
        const int col = task & 255;
        const float alpha = decay[col];
        const float om = 1.0f - alpha;
        float u = caL[cl * OUT_ + col];
        const unsigned short* px = &xt[(cl * LC) * XPAD + col];
        float* po = &out[(size_t)(bm0 + cl * LC) * OUT_ + col];
#pragma unroll
        for (int t = 0; t < LC; ++t) {
            u = fmaf(alpha, u, om * bf2f(px[t * XPAD]));
            po[(size_t)t * OUT_] = u;
        }
    }
}

// ---------------------------------------------------------------------------
// Fallback path (ws too small): fp32 GEMM + simple scan, known good.
// ---------------------------------------------------------------------------
__global__ __launch_bounds__(256) void gemm_bias(const float* __restrict__ A,
                                                 const float* __restrict__ W,
                                                 const float* __restrict__ bias,
                                                 float* __restrict__ C) {
    __shared__ float As[16][64 + 4];
    __shared__ float Ws[16][64 + 4];
    const int bm = blockIdx.y * 64;
    const int bn = blockIdx.x * 64;
    const int tid = threadIdx.x;
    const int tx = tid & 15, ty = tid >> 4;
    const int lr = tid >> 2, lc = (tid & 3) << 2;
    float acc[4][4] = {};
    const float* Ap = A + (size_t)(bm + lr) * IN_ + lc;
    const float* Wp = W + (size_t)(bn + lr) * IN_ + lc;
    for (int k0 = 0; k0 < IN_; k0 += 16) {
        const float4 a = *(const float4*)(Ap + k0);
        const float4 w = *(const float4*)(Wp + k0);
        __syncthreads();
        As[lc + 0][lr] = a.x; As[lc + 1][lr] = a.y; As[lc + 2][lr] = a.z; As[lc + 3][lr] = a.w;
        Ws[lc + 0][lr] = w.x; Ws[lc + 1][lr] = w.y; Ws[lc + 2][lr] = w.z; Ws[lc + 3][lr] = w.w;
        __syncthreads();
#pragma unroll
        for (int kk = 0; kk < 16; ++kk) {
            const float4 av = *(const float4*)&As[kk][ty << 2];
            const float4 wv = *(const float4*)&Ws[kk][tx << 2];
            const float a0[4] = {av.x, av.y, av.z, av.w};
            const float w0[4] = {wv.x, wv.y, wv.z, wv.w};
#pragma unroll
            for (int i = 0; i < 4; ++i)
#pragma unroll
                for (int j = 0; j < 4; ++j) acc[i][j] = fmaf(a0[i], w0[j], acc[i][j]);
        }
    }
#pragma unroll
    for (int i = 0; i < 4; ++i) {
        const size_t row = (size_t)(bm + (ty << 2) + i);
#pragma unroll
        for (int j = 0; j < 4; ++j)
            C[row * OUT_ + bn + (tx << 2) + j] = acc[i][j] + bias[bn + (tx << 2) + j];
    }
}

__global__ __launch_bounds__(OUT_) void scan_simple(float* __restrict__ C,
                                                    const float* __restrict__ decay) {
    const int b = blockIdx.x;
    const int o = threadIdx.x;
    const float alpha = decay[o];
    const float om = 1.0f - alpha;
    float u = 0.0f;
    float* p = C + (size_t)b * T_ * OUT_ + o;
    for (int t = 0; t < T_; ++t) {
        const float x = p[(size_t)t * OUT_];
        u = fmaf(alpha, u, om * x);
        p[(size_t)t * OUT_] = u;
    }
}

extern "C" void kernel_launch(void* const* d_in, const int* in_sizes, int n_in,
                              void* d_out, int out_size, void* d_ws, size_t ws_size,
                              hipStream_t stream) {
    const float* inputs = (const float*)d_in[0];
    const float* weight = (const float*)d_in[1];
    const float* bias   = (const float*)d_in[2];
    const float* decay  = (const float*)d_in[3];
    float* out = (float*)d_out;

    // Workspace layout
    const size_t wb_bytes = (size_t)OUT_ * IN_ * 2;                 // 512 KB bf16 W
    const size_t le_bytes = (size_t)(M_ / BM) * OUT_ * 4;           // 512 KB localend
    const size_t fl_bytes = 4096;                                   // 513 flags+ticket
    const size_t need = wb_bytes + le_bytes + fl_bytes;

    if (ws_size >= need) {
        char* w = (char*)d_ws;
        unsigned short* Wb  = (unsigned short*)w;
        float* localend     = (float*)(w + wb_bytes);
        unsigned int* flags = (unsigned int*)(w + wb_bytes + le_bytes);

        convert_w_init<<<(OUT_ * IN_ / 4) / 256, 256, 0, stream>>>(weight, Wb, flags);
        fused_all<<<M_ / BM, THREADS, 0, stream>>>(inputs, Wb, bias, decay,
                                                   out, localend, flags);
    } else {
        dim3 g(OUT_ / 64, M_ / 64);
        gemm_bias<<<g, 256, 0, stream>>>(inputs, weight, bias, out);
        scan_simple<<<B_, OUT_, 0, stream>>>(out, decay);
    }
}